// Round 8
// baseline (59.307 us; speedup 1.0000x reference)
//
#include <hip/hip_runtime.h>

#define B_ 4
#define C_ 64
#define H_ 128
#define W_ 128
#define LOG2E 1.44269504088896340736f

typedef float v2f __attribute__((ext_vector_type(2)));

__device__ __forceinline__ v2f exp2v(v2f x) {
    return (v2f){ __builtin_amdgcn_exp2f(x.x), __builtin_amdgcn_exp2f(x.y) };
}

// Thread: 4 consecutive x (aligned quad) x 2 consecutive y. All 6 window rows +
// both q quads loaded upfront (deep clause), then pure-register compute.
// HALF=0: rel indexed by window row i; HALF=1: by window col j.
template<int HALF>
__device__ __forceinline__ void sa_body(int x0, int y0,
    const float* __restrict__ f1p, const float* __restrict__ f2p,
    const float* __restrict__ relp, float* __restrict__ outp)
{
    float rel5[5];                       // relp is block-uniform -> scalar loads
    #pragma unroll
    for (int k = 0; k < 5; ++k) rel5[k] = relp[k];

    // x-halo masks and clamped aligned offsets (loop-invariant, per-lane)
    const float mL = (x0 > 0) ? 1.0f : 0.0f;
    const float mR = (x0 < W_ - 4) ? 1.0f : 0.0f;
    const int eM = (x0 >= 4) ? x0 - 4 : 0;
    const int eP = (x0 <= W_ - 8) ? x0 + 4 : W_ - 4;

    // ---- deep load clause: 6 rows x 3 float4 + 2 q float4, then fixup ----
    float w[6][8];                        // window rows y0-2 .. y0+3, cols x0-2 .. x0+5
    #pragma unroll
    for (int t = 0; t < 6; ++t) {
        const int ky = y0 + t - 2;
        const int kycl = ky < 0 ? 0 : (ky > H_ - 1 ? H_ - 1 : ky);
        const float rv = ((unsigned)ky < (unsigned)H_) ? 1.0f : 0.0f;
        const float* rp = f2p + kycl * W_;
        const float4 qm = *(const float4*)(rp + eM);
        const float4 q0 = *(const float4*)(rp + x0);
        const float4 qp = *(const float4*)(rp + eP);
        const float mLr = mL * rv, mRr = mR * rv;
        w[t][0] = qm.z * mLr; w[t][1] = qm.w * mLr;
        w[t][2] = q0.x * rv;  w[t][3] = q0.y * rv;
        w[t][4] = q0.z * rv;  w[t][5] = q0.w * rv;
        w[t][6] = qp.x * mRr; w[t][7] = qp.y * mRr;
    }
    const float4 qrow[2] = { *(const float4*)(f1p + y0 * W_ + x0),
                             *(const float4*)(f1p + (y0 + 1) * W_ + x0) };

    #pragma unroll
    for (int r = 0; r < 2; ++r) {
        const float qs[4] = {qrow[r].x, qrow[r].y, qrow[r].z, qrow[r].w};
        float res[4];

        #pragma unroll
        for (int xo = 0; xo < 4; ++xo) {
            const float q2 = qs[xo] * LOG2E;
            const v2f q2v = {q2, q2};

            float pr[5];
            #pragma unroll
            for (int k = 0; k < 5; ++k) pr[k] = q2 * rel5[k];
            const v2f prA = {pr[0], pr[1]};
            const v2f prB = {pr[2], pr[3]};
            const float prC = pr[4];

            v2f s0 = {0.f, 0.f}, s1 = {0.f, 0.f};
            v2f d0 = {0.f, 0.f}, d1 = {0.f, 0.f};
            float lv[5];

            #pragma unroll
            for (int i = 0; i < 5; ++i) {
                const float* W8 = w[r + i];
                const v2f va = {W8[xo + 0], W8[xo + 1]};
                const v2f vb = {W8[xo + 2], W8[xo + 3]};
                const v2f pa = (HALF == 0) ? (v2f){pr[i], pr[i]} : prA;
                const v2f pb = (HALF == 0) ? (v2f){pr[i], pr[i]} : prB;
                const v2f p0 = exp2v(__builtin_elementwise_fma(va, q2v, pa));
                s0 += p0; d0 = __builtin_elementwise_fma(p0, va, d0);
                const v2f p1 = exp2v(__builtin_elementwise_fma(vb, q2v, pb));
                s1 += p1; d1 = __builtin_elementwise_fma(p1, vb, d1);
                lv[i] = W8[xo + 4];
            }
            {   // leftover column j=4, rows (0,1) packed
                const v2f v  = {lv[0], lv[1]};
                const v2f pp = (HALF == 0) ? (v2f){pr[0], pr[1]} : (v2f){prC, prC};
                const v2f p  = exp2v(__builtin_elementwise_fma(v, q2v, pp));
                s0 += p; d0 = __builtin_elementwise_fma(p, v, d0);
            }
            {   // rows (2,3) packed
                const v2f v  = {lv[2], lv[3]};
                const v2f pp = (HALF == 0) ? (v2f){pr[2], pr[3]} : (v2f){prC, prC};
                const v2f p  = exp2v(__builtin_elementwise_fma(v, q2v, pp));
                s1 += p; d1 = __builtin_elementwise_fma(p, v, d1);
            }
            float ss, ds;
            {   // scalar tail: row 4, col 4
                const float pp = (HALF == 0) ? pr[4] : prC;
                const float p  = __builtin_amdgcn_exp2f(__builtin_fmaf(q2, lv[4], pp));
                ss = p; ds = p * lv[4];
            }
            const v2f st = s0 + s1, dt = d0 + d1;
            res[xo] = (dt.x + dt.y + ds) * __builtin_amdgcn_rcpf(st.x + st.y + ss);
        }

        *(float4*)(outp + (y0 + r) * W_ + x0) = (float4){res[0], res[1], res[2], res[3]};
    }
}

__global__ __launch_bounds__(256, 6) void sa_kernel(
    const float* __restrict__ f1, const float* __restrict__ f2,
    const float* __restrict__ relh, const float* __restrict__ relw,
    float* __restrict__ out)
{
    const int tid = threadIdx.x;
    const int xq  = tid & 31;            // 32 x-quads = full width
    const int ys  = tid >> 5;            // 8 y-strips of 2 rows -> block covers 16 rows
    const int blk = blockIdx.x;
    const int by  = blk & 7;             // 8 blocks per image
    const int bc  = blk >> 3;
    const int c   = bc & (C_ - 1);
    const int b   = bc >> 6;
    const int x0  = xq << 2;
    const int y0  = by * 16 + ys * 2;

    const size_t img = (size_t)(b * C_ + c) * (H_ * W_);
    const float* f1p = f1 + img;
    const float* f2p = f2 + img;

    const int c_out = (c & 7) * 8 + (c >> 3);   // einsum channel transpose
    float* outp = out + (size_t)(b * C_ + c_out) * (H_ * W_);

    if (c < C_ / 2) sa_body<0>(x0, y0, f1p, f2p, relh + c * 5, outp);
    else            sa_body<1>(x0, y0, f1p, f2p, relw + (c - C_ / 2) * 5, outp);
}

extern "C" void kernel_launch(void* const* d_in, const int* in_sizes, int n_in,
                              void* d_out, int out_size, void* d_ws, size_t ws_size,
                              hipStream_t stream) {
    const float* f1   = (const float*)d_in[0];
    const float* f2   = (const float*)d_in[1];
    const float* relh = (const float*)d_in[2];
    const float* relw = (const float*)d_in[3];
    float* out = (float*)d_out;

    const int grid = B_ * C_ * 8;   // 2048 blocks, 8/CU
    sa_kernel<<<grid, 256, 0, stream>>>(f1, f2, relh, relw, out);
}

// Round 9
// 22.533 us; speedup vs baseline: 2.6320x; 2.6320x over previous
//
#include <hip/hip_runtime.h>

#define B_ 4
#define C_ 64
#define H_ 128
#define W_ 128
#define LOG2E 1.44269504088896340736f

typedef float v2f __attribute__((ext_vector_type(2)));

__device__ __forceinline__ v2f exp2v(v2f x) {
    return (v2f){ __builtin_amdgcn_exp2f(x.x), __builtin_amdgcn_exp2f(x.y) };
}

// Thread: 4 consecutive x (aligned quad) x 2 consecutive y. All 6 window rows +
// both q quads loaded upfront (deep clause), then pure-register compute.
// HALF=0: rel indexed by window row i; HALF=1: by window col j.
template<int HALF>
__device__ __forceinline__ void sa_body(int x0, int y0,
    const float* __restrict__ f1p, const float* __restrict__ f2p,
    const float* __restrict__ relp, float* __restrict__ outp)
{
    float rel5[5];                       // relp is block-uniform -> scalar loads
    #pragma unroll
    for (int k = 0; k < 5; ++k) rel5[k] = relp[k];

    // x-halo masks and clamped aligned offsets (loop-invariant, per-lane)
    const float mL = (x0 > 0) ? 1.0f : 0.0f;
    const float mR = (x0 < W_ - 4) ? 1.0f : 0.0f;
    const int eM = (x0 >= 4) ? x0 - 4 : 0;
    const int eP = (x0 <= W_ - 8) ? x0 + 4 : W_ - 4;

    // ---- deep load clause: 6 rows x 3 float4 + 2 q float4, then fixup ----
    float w[6][8];                        // window rows y0-2 .. y0+3, cols x0-2 .. x0+5
    #pragma unroll
    for (int t = 0; t < 6; ++t) {
        const int ky = y0 + t - 2;
        const int kycl = ky < 0 ? 0 : (ky > H_ - 1 ? H_ - 1 : ky);
        const float rv = ((unsigned)ky < (unsigned)H_) ? 1.0f : 0.0f;
        const float* rp = f2p + kycl * W_;
        const float4 qm = *(const float4*)(rp + eM);
        const float4 q0 = *(const float4*)(rp + x0);
        const float4 qp = *(const float4*)(rp + eP);
        const float mLr = mL * rv, mRr = mR * rv;
        w[t][0] = qm.z * mLr; w[t][1] = qm.w * mLr;
        w[t][2] = q0.x * rv;  w[t][3] = q0.y * rv;
        w[t][4] = q0.z * rv;  w[t][5] = q0.w * rv;
        w[t][6] = qp.x * mRr; w[t][7] = qp.y * mRr;
    }
    const float4 qrow[2] = { *(const float4*)(f1p + y0 * W_ + x0),
                             *(const float4*)(f1p + (y0 + 1) * W_ + x0) };

    #pragma unroll
    for (int r = 0; r < 2; ++r) {
        const float qs[4] = {qrow[r].x, qrow[r].y, qrow[r].z, qrow[r].w};
        float res[4];

        #pragma unroll
        for (int xo = 0; xo < 4; ++xo) {
            const float q2 = qs[xo] * LOG2E;
            const v2f q2v = {q2, q2};

            float pr[5];
            #pragma unroll
            for (int k = 0; k < 5; ++k) pr[k] = q2 * rel5[k];
            const v2f prA = {pr[0], pr[1]};
            const v2f prB = {pr[2], pr[3]};
            const float prC = pr[4];

            v2f s0 = {0.f, 0.f}, s1 = {0.f, 0.f};
            v2f d0 = {0.f, 0.f}, d1 = {0.f, 0.f};
            float lv[5];

            #pragma unroll
            for (int i = 0; i < 5; ++i) {
                const float* W8 = w[r + i];
                const v2f va = {W8[xo + 0], W8[xo + 1]};
                const v2f vb = {W8[xo + 2], W8[xo + 3]};
                const v2f pa = (HALF == 0) ? (v2f){pr[i], pr[i]} : prA;
                const v2f pb = (HALF == 0) ? (v2f){pr[i], pr[i]} : prB;
                const v2f p0 = exp2v(__builtin_elementwise_fma(va, q2v, pa));
                s0 += p0; d0 = __builtin_elementwise_fma(p0, va, d0);
                const v2f p1 = exp2v(__builtin_elementwise_fma(vb, q2v, pb));
                s1 += p1; d1 = __builtin_elementwise_fma(p1, vb, d1);
                lv[i] = W8[xo + 4];
            }
            {   // leftover column j=4, rows (0,1) packed
                const v2f v  = {lv[0], lv[1]};
                const v2f pp = (HALF == 0) ? (v2f){pr[0], pr[1]} : (v2f){prC, prC};
                const v2f p  = exp2v(__builtin_elementwise_fma(v, q2v, pp));
                s0 += p; d0 = __builtin_elementwise_fma(p, v, d0);
            }
            {   // rows (2,3) packed
                const v2f v  = {lv[2], lv[3]};
                const v2f pp = (HALF == 0) ? (v2f){pr[2], pr[3]} : (v2f){prC, prC};
                const v2f p  = exp2v(__builtin_elementwise_fma(v, q2v, pp));
                s1 += p; d1 = __builtin_elementwise_fma(p, v, d1);
            }
            float ss, ds;
            {   // scalar tail: row 4, col 4
                const float pp = (HALF == 0) ? pr[4] : prC;
                const float p  = __builtin_amdgcn_exp2f(__builtin_fmaf(q2, lv[4], pp));
                ss = p; ds = p * lv[4];
            }
            const v2f st = s0 + s1, dt = d0 + d1;
            res[xo] = (dt.x + dt.y + ds) * __builtin_amdgcn_rcpf(st.x + st.y + ss);
        }

        *(float4*)(outp + (y0 + r) * W_ + x0) = (float4){res[0], res[1], res[2], res[3]};
    }
}

__global__ __launch_bounds__(256) void sa_kernel(
    const float* __restrict__ f1, const float* __restrict__ f2,
    const float* __restrict__ relh, const float* __restrict__ relw,
    float* __restrict__ out)
{
    const int tid = threadIdx.x;
    const int xq  = tid & 31;            // 32 x-quads = full width
    const int ys  = tid >> 5;            // 8 y-strips of 2 rows -> block covers 16 rows
    const int blk = blockIdx.x;
    const int by  = blk & 7;             // 8 blocks per image
    const int bc  = blk >> 3;
    const int c   = bc & (C_ - 1);
    const int b   = bc >> 6;
    const int x0  = xq << 2;
    const int y0  = by * 16 + ys * 2;

    const size_t img = (size_t)(b * C_ + c) * (H_ * W_);
    const float* f1p = f1 + img;
    const float* f2p = f2 + img;

    const int c_out = (c & 7) * 8 + (c >> 3);   // einsum channel transpose
    float* outp = out + (size_t)(b * C_ + c_out) * (H_ * W_);

    if (c < C_ / 2) sa_body<0>(x0, y0, f1p, f2p, relh + c * 5, outp);
    else            sa_body<1>(x0, y0, f1p, f2p, relw + (c - C_ / 2) * 5, outp);
}

extern "C" void kernel_launch(void* const* d_in, const int* in_sizes, int n_in,
                              void* d_out, int out_size, void* d_ws, size_t ws_size,
                              hipStream_t stream) {
    const float* f1   = (const float*)d_in[0];
    const float* f2   = (const float*)d_in[1];
    const float* relh = (const float*)d_in[2];
    const float* relw = (const float*)d_in[3];
    float* out = (float*)d_out;

    const int grid = B_ * C_ * 8;   // 2048 blocks, 8/CU
    sa_kernel<<<grid, 256, 0, stream>>>(f1, f2, relh, relw, out);
}